// Round 15
// baseline (103.370 us; speedup 1.0000x reference)
//
#include <hip/hip_runtime.h>

#define GRIDN 256
#define BPA 8                     // coarse bins per axis (32 cells each)
#define NBINS (BPA * BPA * BPA)   // 512
#define CAP 6144                  // slots per coarse bin (interior mean 4741, sigma 69)
#define CURSOR_STRIDE 16          // one cursor per 64B line
#define RX 35                     // staged region x-rows: [cbx-2, cbx+33)
#define RY 35
#define RZ 24                     // staged z-extent per pass (aligned)
#define SEGS (RZ / 4)             // float4 segments per row
#define NROWS (RX * RY)           // 1225
#define REGF (NROWS * RZ)         // 29400 floats = 117.6 KB
#define PPT 6                     // records per thread (6*1024 = CAP)

// ---------- shared helpers ----------

__device__ __forceinline__ int cell_guess(float c) {
    float t = (c + 0.64f) * 200.0f;
    int i = (int)t;
    return min(max(i, 0), GRIDN - 1);
}

// exact jnp.searchsorted(p, c, side='left') + clip semantics
__device__ __forceinline__ void dim_interp(float c, const float* __restrict__ p,
                                           int& il, int& ir, float& dl, float& dr) {
    const float SCALE = 0.005f;
    const float OFFSET = -0.64f;
    float t = (c - OFFSET) * (1.0f / SCALE);
    int i = (int)ceilf(t);
    i = min(max(i, 0), GRIDN - 1);
    while (i < GRIDN - 1 && p[i] < c) ++i;
    while (i > 0 && p[i - 1] >= c) --i;
    ir = i;
    il = max(i - 1, 0);
    dl = fmaxf(c - p[il], 0.0f);
    dr = fmaxf(p[ir] - c, 0.0f);
    if (dl == 0.0f && dr == 0.0f) { dl = 1.0f; dr = 1.0f; }
}

// full interp, 8 scalar global gathers (fallback paths only)
__device__ __forceinline__ float interp_point_ax(float cx, float cy, float cz,
                                                 const float* __restrict__ values,
                                                 const float* __restrict__ ax,
                                                 const float* __restrict__ ay,
                                                 const float* __restrict__ az) {
    int ixl, ixr, iyl, iyr, izl, izr;
    float dxl, dxr, dyl, dyr, dzl, dzr;
    dim_interp(cx, ax, ixl, ixr, dxl, dxr);
    dim_interp(cy, ay, iyl, iyr, dyl, dyr);
    dim_interp(cz, az, izl, izr, dzl, dzr);
    int bxl = ixl << 16, bxr = ixr << 16;
    int byl = iyl << 8,  byr = iyr << 8;
    float num =
        values[bxl + byl + izl] * (dxr * dyr * dzr) +
        values[bxl + byl + izr] * (dxr * dyr * dzl) +
        values[bxl + byr + izl] * (dxr * dyl * dzr) +
        values[bxl + byr + izr] * (dxr * dyl * dzl) +
        values[bxr + byl + izl] * (dxl * dyr * dzr) +
        values[bxr + byl + izr] * (dxl * dyr * dzl) +
        values[bxr + byr + izl] * (dxl * dyl * dzr) +
        values[bxr + byr + izr] * (dxl * dyl * dzl);
    float den = (dxl + dxr) * (dyl + dyr) * (dzl + dzr);
    return num / den;
}

// ---------- K1: block-aggregated coarse bin scatter (512 bins, proven) ----------

__global__ __launch_bounds__(1024) void bin_scatter2(
        const float* __restrict__ x, int K,
        unsigned* __restrict__ cursor,     // holds per-bin COUNTS (zero-init)
        float4* __restrict__ records,
        int* __restrict__ inv,
        const float* __restrict__ values,
        const float* __restrict__ px,
        const float* __restrict__ py,
        const float* __restrict__ pz,
        float* __restrict__ out) {
    __shared__ unsigned cnt[NBINS];
    __shared__ unsigned slotcur[NBINS];

    int base = blockIdx.x * 4096;
    int end = min(base + 4096, K);

    for (int t = threadIdx.x; t < NBINS; t += 1024) cnt[t] = 0;
    __syncthreads();

    for (int i = base + threadIdx.x; i < end; i += 1024) {
        int bx = cell_guess(x[3 * i]) >> 5;
        int by = cell_guess(x[3 * i + 1]) >> 5;
        int bz = cell_guess(x[3 * i + 2]) >> 5;
        atomicAdd(&cnt[(bx * BPA + by) * BPA + bz], 1u);
    }
    __syncthreads();

    for (int t = threadIdx.x; t < NBINS; t += 1024)
        slotcur[t] = cnt[t] ? ((unsigned)t * CAP +
                               atomicAdd(&cursor[t * CURSOR_STRIDE], cnt[t]))
                            : 0u;
    __syncthreads();

    for (int i = base + threadIdx.x; i < end; i += 1024) {
        float cx = x[3 * i], cy = x[3 * i + 1], cz = x[3 * i + 2];
        int bx = cell_guess(cx) >> 5;
        int by = cell_guess(cy) >> 5;
        int bz = cell_guess(cz) >> 5;
        int b = (bx * BPA + by) * BPA + bz;
        unsigned s = atomicAdd(&slotcur[b], 1u);
        if (s < (unsigned)((b + 1) * CAP)) {
            records[s] = make_float4(cx, cy, cz, 0.0f);
            inv[i] = (int)s;
        } else {
            inv[i] = -1;   // overflow (statistically never): compute inline
            out[i] = interp_point_ax(cx, cy, cz, values, px, py, pz);
        }
    }
}

// ---------- K2: one block per 32^3-cell bin; LDS-staged values, 2 z-passes ----------

__global__ __launch_bounds__(1024) void interp_staged(
        const float4* __restrict__ records,
        const unsigned* __restrict__ cursor,
        const float* __restrict__ values,
        const float* __restrict__ px,
        const float* __restrict__ py,
        const float* __restrict__ pz,
        float* __restrict__ res) {
    __shared__ float sax[3 * GRIDN];   // 3 KB axes
    __shared__ float reg[REGF];        // 117.6 KB value region (one z-half)

    // bijective XCD swizzle: consecutive (z-adjacent) bins on one XCD ->
    // their x,y row-sets coincide -> L2 reuse of staged lines
    int nb = gridDim.x;                // 512, divisible by 8
    int b = blockIdx.x;
    int q = nb >> 3;
    int bin = (b & 7) * q + (b >> 3);

    for (int t = threadIdx.x; t < GRIDN; t += 1024) {
        sax[t] = px[t];
        sax[GRIDN + t] = py[t];
        sax[2 * GRIDN + t] = pz[t];
    }

    unsigned binstart = (unsigned)bin * CAP;
    int n = min((int)cursor[bin * CURSOR_STRIDE], CAP);

    int cbx = (bin >> 6) << 5;
    int cby = ((bin >> 3) & 7) << 5;
    int cbz = (bin & 7) << 5;
    int rx0 = cbx - 2, ry0 = cby - 2;

    // load this thread's records ONCE into registers (coalesced float4)
    float4 r[PPT];
    #pragma unroll
    for (int k = 0; k < PPT; ++k) {
        int idx = (int)threadIdx.x + k * 1024;
        r[k] = (idx < n) ? records[binstart + idx] : make_float4(0.f, 0.f, 0.f, 0.f);
    }

    for (int pass = 0; pass < 2; ++pass) {
        __syncthreads();   // prev pass compute done (and sax visible on pass 0)
        int z0 = cbz - 4 + pass * 16;   // multiple of 4 -> 16B-aligned rows

        // stage region [RX][RY][RZ]: fully coalesced float4 reads/writes
        for (int l = threadIdx.x; l < NROWS * SEGS; l += 1024) {
            int row = l / SEGS;
            int seg = l - row * SEGS;
            int u = row / RY;
            int v = row - u * RY;
            int gx = min(max(rx0 + u, 0), GRIDN - 1);
            int gy = min(max(ry0 + v, 0), GRIDN - 1);
            int gz = min(max(z0 + seg * 4, 0), GRIDN - 4);   // clamped: guard slots
            float4 val = *reinterpret_cast<const float4*>(
                &values[(gx << 16) | (gy << 8) | gz]);
            *reinterpret_cast<float4*>(&reg[row * RZ + seg * 4]) = val;
        }
        __syncthreads();

        // compute points whose z-guess falls in this z-half
        #pragma unroll
        for (int k = 0; k < PPT; ++k) {
            int idx = (int)threadIdx.x + k * 1024;
            if (idx >= n) continue;
            float4 rc = r[k];
            if (((cell_guess(rc.z) - cbz) >> 4) != pass) continue;

            int ixl, ixr, iyl, iyr, izl, izr;
            float dxl, dxr, dyl, dyr, dzl, dzr;
            dim_interp(rc.x, sax,             ixl, ixr, dxl, dxr);
            dim_interp(rc.y, sax + GRIDN,     iyl, iyr, dyl, dyr);
            dim_interp(rc.z, sax + 2 * GRIDN, izl, izr, dzl, dzr);

            int lx = ixl - rx0, ly = iyl - ry0, lz = izl - z0;
            float outv;
            if ((unsigned)lx < RX - 1 && (unsigned)ly < RY - 1 &&
                (unsigned)lz < RZ - 1 &&
                ixr == ixl + 1 && iyr == iyl + 1 && izr == izl + 1) {
                const float* p00 = &reg[(lx * RY + ly) * RZ + lz];
                const float* p01 = &reg[(lx * RY + (ly + 1)) * RZ + lz];
                const float* p10 = &reg[((lx + 1) * RY + ly) * RZ + lz];
                const float* p11 = &reg[((lx + 1) * RY + (ly + 1)) * RZ + lz];
                float num =
                    (dxr * dyr) * (p00[0] * dzr + p00[1] * dzl) +
                    (dxr * dyl) * (p01[0] * dzr + p01[1] * dzl) +
                    (dxl * dyr) * (p10[0] * dzr + p10[1] * dzl) +
                    (dxl * dyl) * (p11[0] * dzr + p11[1] * dzl);
                float den = (dxl + dxr) * (dyl + dyr) * (dzl + dzr);
                outv = num / den;
            } else {
                // index wandered outside staged window (rare/never): global path
                outv = interp_point_ax(rc.x, rc.y, rc.z, values, px, py, pz);
            }
            res[binstart + idx] = outv;
        }
    }
}

// ---------- K3: unscatter results to original order ----------

__global__ void unscatter(const int* __restrict__ inv,
                          const float* __restrict__ res,
                          float* __restrict__ out, int K) {
    int i = blockIdx.x * blockDim.x + threadIdx.x;
    if (i >= K) return;
    int s = inv[i];
    if (s >= 0) out[i] = res[s];
}

// ---------- fallback: direct (round-1) kernel ----------

__global__ void trilerp_direct(const float* __restrict__ x,
                               const float* __restrict__ values,
                               const float* __restrict__ px,
                               const float* __restrict__ py,
                               const float* __restrict__ pz,
                               float* __restrict__ out, int K) {
    int i = blockIdx.x * blockDim.x + threadIdx.x;
    if (i >= K) return;
    out[i] = interp_point_ax(x[3 * i], x[3 * i + 1], x[3 * i + 2],
                             values, px, py, pz);
}

extern "C" void kernel_launch(void* const* d_in, const int* in_sizes, int n_in,
                              void* d_out, int out_size, void* d_ws, size_t ws_size,
                              hipStream_t stream) {
    const float* x      = (const float*)d_in[0];
    const float* values = (const float*)d_in[1];
    const float* px     = (const float*)d_in[2];
    const float* py     = (const float*)d_in[3];
    const float* pz     = (const float*)d_in[4];
    float* out = (float*)d_out;

    int K = in_sizes[0] / 3;

    size_t cursor_bytes  = (size_t)NBINS * CURSOR_STRIDE * 4;   // 32 KB
    size_t records_bytes = (size_t)NBINS * CAP * 16;            // 50.3 MB
    size_t inv_bytes     = (size_t)K * 4;                       // 8 MB
    size_t res_bytes     = (size_t)NBINS * CAP * 4;             // 12.6 MB
    size_t need = cursor_bytes + records_bytes + inv_bytes + res_bytes;

    if (ws_size < need) {
        int grid = (K + 255) / 256;
        trilerp_direct<<<grid, 256, 0, stream>>>(x, values, px, py, pz, out, K);
        return;
    }

    char* p = (char*)d_ws;
    unsigned* cursor = (unsigned*)p;  p += cursor_bytes;
    float4* records  = (float4*)p;    p += records_bytes;
    int* inv         = (int*)p;       p += inv_bytes;
    float* res       = (float*)p;

    hipMemsetAsync(cursor, 0, cursor_bytes, stream);

    int nblk1 = (K + 4095) / 4096;
    bin_scatter2<<<nblk1, 1024, 0, stream>>>(x, K, cursor, records, inv,
                                             values, px, py, pz, out);

    interp_staged<<<NBINS, 1024, 0, stream>>>(records, cursor,
                                              values, px, py, pz, res);

    int nblk3 = (K + 255) / 256;
    unscatter<<<nblk3, 256, 0, stream>>>(inv, res, out, K);
}

// Round 16
// 90.936 us; speedup vs baseline: 1.1367x; 1.1367x over previous
//
#include <hip/hip_runtime.h>

#define GRIDN 256
#define BPA 8                     // coarse bins per axis (32 cells each)
#define NBINS (BPA * BPA * BPA)   // 512
#define CAP 6144                  // slots per coarse bin (interior mean 4741, sigma 69)
#define HALF 2                    // K2 blocks per bin (slot-range split)
#define CAPH (CAP / HALF)         // 3072 pts per K2 block
#define CURSOR_STRIDE 16          // one cursor per 64B line
#define FKEYS 512                 // fine keys: 8x8x8 sub-bins of 4x4x4 cells, z fastest

// ---------- shared helpers ----------

__device__ __forceinline__ int cell_guess(float c) {
    float t = (c + 0.64f) * 200.0f;
    int i = (int)t;
    return min(max(i, 0), GRIDN - 1);
}

// axis value EXACTLY as jnp computes it: fl(fl(i*0.005f) + (-0.64f)),
// forced separate roundings (no FMA contraction)
__device__ __forceinline__ float axv(int i) {
    return __fadd_rn(__fmul_rn((float)i, 0.005f), -0.64f);
}

// exact jnp.searchsorted(p, c, side='left') + clip semantics against GLOBAL
// axis arrays (fallback paths only)
__device__ __forceinline__ void dim_interp(float c, const float* __restrict__ p,
                                           int& il, int& ir, float& dl, float& dr) {
    const float SCALE = 0.005f;
    const float OFFSET = -0.64f;
    float t = (c - OFFSET) * (1.0f / SCALE);
    int i = (int)ceilf(t);
    i = min(max(i, 0), GRIDN - 1);
    while (i < GRIDN - 1 && p[i] < c) ++i;
    while (i > 0 && p[i - 1] >= c) --i;
    ir = i;
    il = max(i - 1, 0);
    dl = fmaxf(c - p[il], 0.0f);
    dr = fmaxf(p[ir] - c, 0.0f);
    if (dl == 0.0f && dr == 0.0f) { dl = 1.0f; dr = 1.0f; }
}

// arithmetic-axis searchsorted: identical result, zero memory reads.
// c in (-0.6,0.6) -> result interior (ir in [8,248]), so no clamp cases.
__device__ __forceinline__ void dim_interp_arith(float c, int& il, int& ir,
                                                 float& dl, float& dr) {
    float t = (c + 0.64f) * 200.0f;
    int i = (int)ceilf(t);
    i = min(max(i, 1), GRIDN - 1);
    while (i < GRIDN - 1 && axv(i) < c) ++i;
    while (i > 1 && axv(i - 1) >= c) --i;
    ir = i;
    il = i - 1;
    dl = fmaxf(c - axv(il), 0.0f);
    dr = fmaxf(axv(ir) - c, 0.0f);
}

// full interp, 8 scalar global gathers (rare fallback paths only)
__device__ __forceinline__ float interp_point_ax(float cx, float cy, float cz,
                                                 const float* __restrict__ values,
                                                 const float* __restrict__ ax,
                                                 const float* __restrict__ ay,
                                                 const float* __restrict__ az) {
    int ixl, ixr, iyl, iyr, izl, izr;
    float dxl, dxr, dyl, dyr, dzl, dzr;
    dim_interp(cx, ax, ixl, ixr, dxl, dxr);
    dim_interp(cy, ay, iyl, iyr, dyl, dyr);
    dim_interp(cz, az, izl, izr, dzl, dzr);
    int bxl = ixl << 16, bxr = ixr << 16;
    int byl = iyl << 8,  byr = iyr << 8;
    float num =
        values[bxl + byl + izl] * (dxr * dyr * dzr) +
        values[bxl + byl + izr] * (dxr * dyr * dzl) +
        values[bxl + byr + izl] * (dxr * dyl * dzr) +
        values[bxl + byr + izr] * (dxr * dyl * dzl) +
        values[bxr + byl + izl] * (dxl * dyr * dzr) +
        values[bxr + byl + izr] * (dxl * dyr * dzl) +
        values[bxr + byr + izl] * (dxl * dyl * dzr) +
        values[bxr + byr + izr] * (dxl * dyl * dzl);
    float den = (dxl + dxr) * (dyl + dyr) * (dzl + dzr);
    return num / den;
}

// arithmetic-axis interp with z-pair dwordx2 gathers (4 memory ops, no LDS).
// Interior points: izr == izl+1 always, float2 at izl in-bounds.
__device__ __forceinline__ float interp_zpair_arith(float cx, float cy, float cz,
                                                    const float* __restrict__ values) {
    int ixl, ixr, iyl, iyr, izl, izr;
    float dxl, dxr, dyl, dyr, dzl, dzr;
    dim_interp_arith(cx, ixl, ixr, dxl, dxr);
    dim_interp_arith(cy, iyl, iyr, dyl, dyr);
    dim_interp_arith(cz, izl, izr, dzl, dzr);

    int bxl = ixl << 16, bxr = ixr << 16;
    int byl = iyl << 8,  byr = iyr << 8;

    float2 vll, vlr, vrl, vrr;
    __builtin_memcpy(&vll, &values[bxl + byl + izl], 8);
    __builtin_memcpy(&vlr, &values[bxl + byr + izl], 8);
    __builtin_memcpy(&vrl, &values[bxr + byl + izl], 8);
    __builtin_memcpy(&vrr, &values[bxr + byr + izl], 8);

    float num =
        (dxr * dyr) * (vll.x * dzr + vll.y * dzl) +
        (dxr * dyl) * (vlr.x * dzr + vlr.y * dzl) +
        (dxl * dyr) * (vrl.x * dzr + vrl.y * dzl) +
        (dxl * dyl) * (vrr.x * dzr + vrr.y * dzl);
    float den = (dxl + dxr) * (dyl + dyr) * (dzl + dzr);
    return num / den;
}

// ---------- K1: block-aggregated coarse bin scatter (512 bins, proven) ----------

__global__ __launch_bounds__(1024) void bin_scatter2(
        const float* __restrict__ x, int K,
        unsigned* __restrict__ cursor,     // holds per-bin COUNTS (zero-init)
        float4* __restrict__ records,
        int* __restrict__ inv,
        const float* __restrict__ values,
        const float* __restrict__ px,
        const float* __restrict__ py,
        const float* __restrict__ pz,
        float* __restrict__ out) {
    __shared__ unsigned cnt[NBINS];
    __shared__ unsigned slotcur[NBINS];

    int base = blockIdx.x * 4096;
    int end = min(base + 4096, K);

    for (int t = threadIdx.x; t < NBINS; t += 1024) cnt[t] = 0;
    __syncthreads();

    for (int i = base + threadIdx.x; i < end; i += 1024) {
        int bx = cell_guess(x[3 * i]) >> 5;
        int by = cell_guess(x[3 * i + 1]) >> 5;
        int bz = cell_guess(x[3 * i + 2]) >> 5;
        atomicAdd(&cnt[(bx * BPA + by) * BPA + bz], 1u);
    }
    __syncthreads();

    for (int t = threadIdx.x; t < NBINS; t += 1024)
        slotcur[t] = cnt[t] ? ((unsigned)t * CAP +
                               atomicAdd(&cursor[t * CURSOR_STRIDE], cnt[t]))
                            : 0u;
    __syncthreads();

    for (int i = base + threadIdx.x; i < end; i += 1024) {
        float cx = x[3 * i], cy = x[3 * i + 1], cz = x[3 * i + 2];
        int bx = cell_guess(cx) >> 5;
        int by = cell_guess(cy) >> 5;
        int bz = cell_guess(cz) >> 5;
        int b = (bx * BPA + by) * BPA + bz;
        unsigned s = atomicAdd(&slotcur[b], 1u);
        if (s < (unsigned)((b + 1) * CAP)) {
            records[s] = make_float4(cx, cy, cz, 0.0f);
            inv[i] = (int)s;
        } else {
            inv[i] = -1;   // overflow (statistically never): compute inline
            out[i] = interp_point_ax(cx, cy, cz, values, px, py, pz);
        }
    }
}

// ---------- K2: 2 blocks/bin; sort points INTO LDS; block-stride walk ----------

#define K2_THREADS 1024

__global__ __launch_bounds__(K2_THREADS) void interp_sorted2(
        const float4* __restrict__ records,
        const unsigned* __restrict__ cursor,
        const float* __restrict__ values,
        float* __restrict__ res) {
    __shared__ unsigned hist[FKEYS];     // 2 KB
    __shared__ unsigned wsum[8];
    __shared__ float4 spts[CAPH];        // 48 KB: fine-SORTED points, orig slot in .w
    __shared__ float sres[CAPH];         // 12 KB   (total ~62 KB -> 2 blocks/CU)

    // bijective XCD swizzle; halves of a bin adjacent on the same XCD
    int nb = gridDim.x;               // 1024, divisible by 8
    int b = blockIdx.x;
    int q = nb >> 3;
    int lin = (b & 7) * q + (b >> 3);
    int bin = lin >> 1;
    int half = lin & 1;

    for (int t = threadIdx.x; t < FKEYS; t += K2_THREADS) hist[t] = 0;
    __syncthreads();

    unsigned binstart = (unsigned)bin * CAP;
    int npts = min((int)cursor[bin * CURSOR_STRIDE], CAP);
    if (npts <= 0) return;

    int cnt_h = (npts + HALF - 1) / HALF;      // <= CAPH
    int lo = half * cnt_h;
    int n = min(npts, lo + cnt_h) - lo;
    if (n <= 0) return;
    unsigned base = binstart + lo;

    int cbx = (bin >> 6) << 5;
    int cby = ((bin >> 3) & 7) << 5;
    int cbz = (bin & 7) << 5;

    // phase 1: coalesced read of records; histogram of 4^3-cell fine keys
    for (int pt = threadIdx.x; pt < n; pt += K2_THREADS) {
        float4 rec = records[base + pt];
        int fx = (cell_guess(rec.x) - cbx) >> 2;
        int fy = (cell_guess(rec.y) - cby) >> 2;
        int fz = (cell_guess(rec.z) - cbz) >> 2;
        fx = min(max(fx, 0), 7); fy = min(max(fy, 0), 7); fz = min(max(fz, 0), 7);
        atomicAdd(&hist[(((fx << 3) | fy) << 3) | fz], 1u);
    }
    __syncthreads();

    // phase 2: hierarchical exclusive scan of 512 counts (3 barriers)
    unsigned v = 0, s = 0;
    int lane = threadIdx.x & 63, w = threadIdx.x >> 6;
    if (threadIdx.x < FKEYS) {
        v = hist[threadIdx.x];
        s = v;
        for (int off = 1; off < 64; off <<= 1) {
            unsigned t = __shfl_up(s, off, 64);
            if (lane >= off) s += t;
        }
        if (lane == 63) wsum[w] = s;
    }
    __syncthreads();
    if (threadIdx.x == 0) {
        unsigned a = 0;
        for (int i = 0; i < 8; ++i) { unsigned t = wsum[i]; wsum[i] = a; a += t; }
    }
    __syncthreads();
    if (threadIdx.x < FKEYS) hist[threadIdx.x] = s - v + wsum[w];   // exclusive
    __syncthreads();

    // phase 3: re-read records (L1/L2-hot) and scatter SORTED into LDS,
    // carrying the original slot offset in .w
    for (int pt = threadIdx.x; pt < n; pt += K2_THREADS) {
        float4 rec = records[base + pt];
        int fx = (cell_guess(rec.x) - cbx) >> 2;
        int fy = (cell_guess(rec.y) - cby) >> 2;
        int fz = (cell_guess(rec.z) - cbz) >> 2;
        fx = min(max(fx, 0), 7); fy = min(max(fy, 0), 7); fz = min(max(fz, 0), 7);
        unsigned slot = atomicAdd(&hist[(((fx << 3) | fy) << 3) | fz], 1u);
        spts[slot] = make_float4(rec.x, rec.y, rec.z, __int_as_float(pt));
    }
    __syncthreads();

    // phase 4: R11's plain block-stride walk over the sorted order.
    // Per point: ONE ds_read_b128 + 4 z-pair gathers + ONE ds_write;
    // index calc fully arithmetic (zero axis memory reads).
    for (int pt = threadIdx.x; pt < n; pt += K2_THREADS) {
        float4 r = spts[pt];
        float val = interp_zpair_arith(r.x, r.y, r.z, values);
        sres[__float_as_int(r.w)] = val;
    }
    __syncthreads();

    // phase 5: dense coalesced writeout (original slot order preserved)
    for (int pt = threadIdx.x; pt < n; pt += K2_THREADS)
        res[base + pt] = sres[pt];
}

// ---------- K3: unscatter results to original order ----------

__global__ void unscatter(const int* __restrict__ inv,
                          const float* __restrict__ res,
                          float* __restrict__ out, int K) {
    int i = blockIdx.x * blockDim.x + threadIdx.x;
    if (i >= K) return;
    int s = inv[i];
    if (s >= 0) out[i] = res[s];
}

// ---------- fallback: direct (round-1) kernel ----------

__global__ void trilerp_direct(const float* __restrict__ x,
                               const float* __restrict__ values,
                               const float* __restrict__ px,
                               const float* __restrict__ py,
                               const float* __restrict__ pz,
                               float* __restrict__ out, int K) {
    int i = blockIdx.x * blockDim.x + threadIdx.x;
    if (i >= K) return;
    out[i] = interp_point_ax(x[3 * i], x[3 * i + 1], x[3 * i + 2],
                             values, px, py, pz);
}

extern "C" void kernel_launch(void* const* d_in, const int* in_sizes, int n_in,
                              void* d_out, int out_size, void* d_ws, size_t ws_size,
                              hipStream_t stream) {
    const float* x      = (const float*)d_in[0];
    const float* values = (const float*)d_in[1];
    const float* px     = (const float*)d_in[2];
    const float* py     = (const float*)d_in[3];
    const float* pz     = (const float*)d_in[4];
    float* out = (float*)d_out;

    int K = in_sizes[0] / 3;

    size_t cursor_bytes  = (size_t)NBINS * CURSOR_STRIDE * 4;   // 32 KB
    size_t records_bytes = (size_t)NBINS * CAP * 16;            // 50.3 MB
    size_t inv_bytes     = (size_t)K * 4;                       // 8 MB
    size_t res_bytes     = (size_t)NBINS * CAP * 4;             // 12.6 MB
    size_t need = cursor_bytes + records_bytes + inv_bytes + res_bytes;

    if (ws_size < need) {
        int grid = (K + 255) / 256;
        trilerp_direct<<<grid, 256, 0, stream>>>(x, values, px, py, pz, out, K);
        return;
    }

    char* p = (char*)d_ws;
    unsigned* cursor = (unsigned*)p;  p += cursor_bytes;
    float4* records  = (float4*)p;    p += records_bytes;
    int* inv         = (int*)p;       p += inv_bytes;
    float* res       = (float*)p;

    hipMemsetAsync(cursor, 0, cursor_bytes, stream);

    int nblk1 = (K + 4095) / 4096;
    bin_scatter2<<<nblk1, 1024, 0, stream>>>(x, K, cursor, records, inv,
                                             values, px, py, pz, out);

    interp_sorted2<<<NBINS * HALF, K2_THREADS, 0, stream>>>(records, cursor,
                                                            values, res);

    int nblk3 = (K + 255) / 256;
    unscatter<<<nblk3, 256, 0, stream>>>(inv, res, out, K);
}

// Round 17
// 82.388 us; speedup vs baseline: 1.2547x; 1.1038x over previous
//
#include <hip/hip_runtime.h>

#define GRIDN 256
#define BPA 8                     // coarse bins per axis (32 cells each)
#define NBINS (BPA * BPA * BPA)   // 512
#define CAP 6144                  // slots per coarse bin (interior mean 4741, sigma 69)
#define HALF 2                    // K2 blocks per bin (slot-range split)
#define CAPH (CAP / HALF)         // 3072 pts per K2 block
#define CURSOR_STRIDE 16          // one cursor per 64B line
#define FKEYS 512                 // fine keys: 8x8x8 sub-bins of 4x4x4 cells, z fastest

// ---------- shared helpers ----------

__device__ __forceinline__ int cell_guess(float c) {
    float t = (c + 0.64f) * 200.0f;
    int i = (int)t;
    return min(max(i, 0), GRIDN - 1);
}

// exact jnp.searchsorted(p, c, side='left') + clip semantics
__device__ __forceinline__ void dim_interp(float c, const float* __restrict__ p,
                                           int& il, int& ir, float& dl, float& dr) {
    const float SCALE = 0.005f;
    const float OFFSET = -0.64f;
    float t = (c - OFFSET) * (1.0f / SCALE);
    int i = (int)ceilf(t);
    i = min(max(i, 0), GRIDN - 1);
    while (i < GRIDN - 1 && p[i] < c) ++i;
    while (i > 0 && p[i - 1] >= c) --i;
    ir = i;
    il = max(i - 1, 0);
    dl = fmaxf(c - p[il], 0.0f);
    dr = fmaxf(p[ir] - c, 0.0f);
    if (dl == 0.0f && dr == 0.0f) { dl = 1.0f; dr = 1.0f; }
}

// full interp, 8 scalar gathers (rare fallback paths only)
__device__ __forceinline__ float interp_point_ax(float cx, float cy, float cz,
                                                 const float* __restrict__ values,
                                                 const float* __restrict__ ax,
                                                 const float* __restrict__ ay,
                                                 const float* __restrict__ az) {
    int ixl, ixr, iyl, iyr, izl, izr;
    float dxl, dxr, dyl, dyr, dzl, dzr;
    dim_interp(cx, ax, ixl, ixr, dxl, dxr);
    dim_interp(cy, ay, iyl, iyr, dyl, dyr);
    dim_interp(cz, az, izl, izr, dzl, dzr);
    int bxl = ixl << 16, bxr = ixr << 16;
    int byl = iyl << 8,  byr = iyr << 8;
    float num =
        values[bxl + byl + izl] * (dxr * dyr * dzr) +
        values[bxl + byl + izr] * (dxr * dyr * dzl) +
        values[bxl + byr + izl] * (dxr * dyl * dzr) +
        values[bxl + byr + izr] * (dxr * dyl * dzl) +
        values[bxr + byl + izl] * (dxl * dyr * dzr) +
        values[bxr + byl + izr] * (dxl * dyr * dzl) +
        values[bxr + byr + izl] * (dxl * dyl * dzr) +
        values[bxr + byr + izr] * (dxl * dyl * dzl);
    float den = (dxl + dxr) * (dyl + dyr) * (dzl + dzr);
    return num / den;
}

// interp with z-pair dwordx2 gathers (4 memory ops). ir in {il, il+1};
// izl <= 254 so the float2 is in-bounds; select .x when izr==izl.
__device__ __forceinline__ float interp_zpair(float cx, float cy, float cz,
                                              const float* __restrict__ values,
                                              const float* __restrict__ sax) {
    int ixl, ixr, iyl, iyr, izl, izr;
    float dxl, dxr, dyl, dyr, dzl, dzr;
    dim_interp(cx, sax,             ixl, ixr, dxl, dxr);
    dim_interp(cy, sax + GRIDN,     iyl, iyr, dyl, dyr);
    dim_interp(cz, sax + 2 * GRIDN, izl, izr, dzl, dzr);

    int bxl = ixl << 16, bxr = ixr << 16;
    int byl = iyl << 8,  byr = iyr << 8;

    float2 vll, vlr, vrl, vrr;
    __builtin_memcpy(&vll, &values[bxl + byl + izl], 8);
    __builtin_memcpy(&vlr, &values[bxl + byr + izl], 8);
    __builtin_memcpy(&vrl, &values[bxr + byl + izl], 8);
    __builtin_memcpy(&vrr, &values[bxr + byr + izl], 8);

    bool zsame = (izr == izl);
    float zll = vll.x, zlr = zsame ? vll.x : vll.y;
    float yll = vlr.x, ylr = zsame ? vlr.x : vlr.y;
    float xll = vrl.x, xlr = zsame ? vrl.x : vrl.y;
    float wll = vrr.x, wlr = zsame ? vrr.x : vrr.y;

    float num =
        (dxr * dyr) * (zll * dzr + zlr * dzl) +
        (dxr * dyl) * (yll * dzr + ylr * dzl) +
        (dxl * dyr) * (xll * dzr + xlr * dzl) +
        (dxl * dyl) * (wll * dzr + wlr * dzl);
    float den = (dxl + dxr) * (dyl + dyr) * (dzl + dzr);
    return num / den;
}

// ---------- K1: block-aggregated coarse bin scatter (512 bins, proven) ----------

__global__ __launch_bounds__(1024) void bin_scatter2(
        const float* __restrict__ x, int K,
        unsigned* __restrict__ cursor,     // holds per-bin COUNTS (zero-init)
        float4* __restrict__ records,
        int* __restrict__ inv,
        const float* __restrict__ values,
        const float* __restrict__ px,
        const float* __restrict__ py,
        const float* __restrict__ pz,
        float* __restrict__ out) {
    __shared__ unsigned cnt[NBINS];
    __shared__ unsigned slotcur[NBINS];

    int base = blockIdx.x * 4096;
    int end = min(base + 4096, K);

    for (int t = threadIdx.x; t < NBINS; t += 1024) cnt[t] = 0;
    __syncthreads();

    for (int i = base + threadIdx.x; i < end; i += 1024) {
        int bx = cell_guess(x[3 * i]) >> 5;
        int by = cell_guess(x[3 * i + 1]) >> 5;
        int bz = cell_guess(x[3 * i + 2]) >> 5;
        atomicAdd(&cnt[(bx * BPA + by) * BPA + bz], 1u);
    }
    __syncthreads();

    for (int t = threadIdx.x; t < NBINS; t += 1024)
        slotcur[t] = cnt[t] ? ((unsigned)t * CAP +
                               atomicAdd(&cursor[t * CURSOR_STRIDE], cnt[t]))
                            : 0u;
    __syncthreads();

    for (int i = base + threadIdx.x; i < end; i += 1024) {
        float cx = x[3 * i], cy = x[3 * i + 1], cz = x[3 * i + 2];
        int bx = cell_guess(cx) >> 5;
        int by = cell_guess(cy) >> 5;
        int bz = cell_guess(cz) >> 5;
        int b = (bx * BPA + by) * BPA + bz;
        unsigned s = atomicAdd(&slotcur[b], 1u);
        if (s < (unsigned)((b + 1) * CAP)) {
            records[s] = make_float4(cx, cy, cz, 0.0f);
            inv[i] = (int)s;
        } else {
            inv[i] = -1;   // overflow (statistically never): compute inline
            out[i] = interp_point_ax(cx, cy, cz, values, px, py, pz);
        }
    }
}

// ---------- K2: 2 blocks per coarse bin (slot-split); 512-key fine z-sort ----------

#define K2_THREADS 1024

__global__ __launch_bounds__(K2_THREADS) void interp_halfsort(
        const float4* __restrict__ records,
        const unsigned* __restrict__ cursor,
        const float* __restrict__ values,
        const float* __restrict__ px,
        const float* __restrict__ py,
        const float* __restrict__ pz,
        float* __restrict__ res) {
    __shared__ float sax[3 * GRIDN];              // 3 KB
    __shared__ unsigned hist[FKEYS];              // 2 KB
    __shared__ unsigned wsum[8];
    __shared__ unsigned short skeys[CAPH];        // 6 KB
    __shared__ unsigned short order[CAPH];        // 6 KB
    __shared__ float sx[CAPH], sy[CAPH], sz[CAPH]; // 36 KB
    __shared__ float sres[CAPH];                  // 12 KB  (total ~65 KB -> 2/CU)

    // bijective XCD swizzle; lin consecutive -> same XCD, halves of a bin adjacent
    int nb = gridDim.x;               // 1024, divisible by 8
    int b = blockIdx.x;
    int q = nb >> 3;
    int lin = (b & 7) * q + (b >> 3);
    int bin = lin >> 1;
    int half = lin & 1;

    for (int t = threadIdx.x; t < GRIDN; t += K2_THREADS) {
        sax[t] = px[t];
        sax[GRIDN + t] = py[t];
        sax[2 * GRIDN + t] = pz[t];
    }
    for (int t = threadIdx.x; t < FKEYS; t += K2_THREADS) hist[t] = 0;
    __syncthreads();

    unsigned binstart = (unsigned)bin * CAP;
    int npts = min((int)cursor[bin * CURSOR_STRIDE], CAP);
    if (npts <= 0) return;

    int cnt_h = (npts + HALF - 1) / HALF;      // <= CAPH
    int lo = half * cnt_h;
    int n = min(npts, lo + cnt_h) - lo;
    if (n <= 0) return;
    unsigned base = binstart + lo;

    int cbx = (bin >> 6) << 5;
    int cby = ((bin >> 3) & 7) << 5;
    int cbz = (bin & 7) << 5;

    // phase 1: coalesced read of the half's records -> LDS; 4^3-cell key + hist
    for (int pt = threadIdx.x; pt < n; pt += K2_THREADS) {
        float4 rec = records[base + pt];
        sx[pt] = rec.x; sy[pt] = rec.y; sz[pt] = rec.z;
        int fx = (cell_guess(rec.x) - cbx) >> 2;
        int fy = (cell_guess(rec.y) - cby) >> 2;
        int fz = (cell_guess(rec.z) - cbz) >> 2;
        fx = min(max(fx, 0), 7); fy = min(max(fy, 0), 7); fz = min(max(fz, 0), 7);
        int k = (((fx << 3) | fy) << 3) | fz;   // z fastest -> sorted order z-local
        skeys[pt] = (unsigned short)k;
        atomicAdd(&hist[k], 1u);
    }
    __syncthreads();

    // phase 2: hierarchical exclusive scan of 512 counts (3 barriers)
    unsigned v = 0, s = 0;
    int lane = threadIdx.x & 63, w = threadIdx.x >> 6;
    if (threadIdx.x < FKEYS) {
        v = hist[threadIdx.x];
        s = v;
        for (int off = 1; off < 64; off <<= 1) {
            unsigned t = __shfl_up(s, off, 64);
            if (lane >= off) s += t;
        }
        if (lane == 63) wsum[w] = s;    // wave-chunk inclusive total
    }
    __syncthreads();
    if (threadIdx.x == 0) {
        unsigned a = 0;
        for (int i = 0; i < 8; ++i) { unsigned t = wsum[i]; wsum[i] = a; a += t; }
    }
    __syncthreads();
    if (threadIdx.x < FKEYS) hist[threadIdx.x] = s - v + wsum[w];   // exclusive
    __syncthreads();

    // phase 3: scatter point indices into fine-sorted order
    for (int pt = threadIdx.x; pt < n; pt += K2_THREADS) {
        unsigned slot = atomicAdd(&hist[skeys[pt]], 1u);
        order[slot] = (unsigned short)pt;
    }
    __syncthreads();

    // phase 4: process in z-sorted order; point data from LDS; z-pair gathers
    for (int pt = threadIdx.x; pt < n; pt += K2_THREADS) {
        int j = order[pt];
        sres[j] = interp_zpair(sx[j], sy[j], sz[j], values, sax);
    }
    __syncthreads();

    // phase 5: dense coalesced writeout
    for (int pt = threadIdx.x; pt < n; pt += K2_THREADS)
        res[base + pt] = sres[pt];
}

// ---------- K3: unscatter results to original order ----------

__global__ void unscatter(const int* __restrict__ inv,
                          const float* __restrict__ res,
                          float* __restrict__ out, int K) {
    int i = blockIdx.x * blockDim.x + threadIdx.x;
    if (i >= K) return;
    int s = inv[i];
    if (s >= 0) out[i] = res[s];
}

// ---------- fallback: direct (round-1) kernel ----------

__global__ void trilerp_direct(const float* __restrict__ x,
                               const float* __restrict__ values,
                               const float* __restrict__ px,
                               const float* __restrict__ py,
                               const float* __restrict__ pz,
                               float* __restrict__ out, int K) {
    int i = blockIdx.x * blockDim.x + threadIdx.x;
    if (i >= K) return;
    out[i] = interp_point_ax(x[3 * i], x[3 * i + 1], x[3 * i + 2],
                             values, px, py, pz);
}

extern "C" void kernel_launch(void* const* d_in, const int* in_sizes, int n_in,
                              void* d_out, int out_size, void* d_ws, size_t ws_size,
                              hipStream_t stream) {
    const float* x      = (const float*)d_in[0];
    const float* values = (const float*)d_in[1];
    const float* px     = (const float*)d_in[2];
    const float* py     = (const float*)d_in[3];
    const float* pz     = (const float*)d_in[4];
    float* out = (float*)d_out;

    int K = in_sizes[0] / 3;

    size_t cursor_bytes  = (size_t)NBINS * CURSOR_STRIDE * 4;   // 32 KB
    size_t records_bytes = (size_t)NBINS * CAP * 16;            // 50.3 MB
    size_t inv_bytes     = (size_t)K * 4;                       // 8 MB
    size_t res_bytes     = (size_t)NBINS * CAP * 4;             // 12.6 MB
    size_t need = cursor_bytes + records_bytes + inv_bytes + res_bytes;

    if (ws_size < need) {
        int grid = (K + 255) / 256;
        trilerp_direct<<<grid, 256, 0, stream>>>(x, values, px, py, pz, out, K);
        return;
    }

    char* p = (char*)d_ws;
    unsigned* cursor = (unsigned*)p;  p += cursor_bytes;
    float4* records  = (float4*)p;    p += records_bytes;
    int* inv         = (int*)p;       p += inv_bytes;
    float* res       = (float*)p;

    hipMemsetAsync(cursor, 0, cursor_bytes, stream);

    int nblk1 = (K + 4095) / 4096;
    bin_scatter2<<<nblk1, 1024, 0, stream>>>(x, K, cursor, records, inv,
                                             values, px, py, pz, out);

    interp_halfsort<<<NBINS * HALF, K2_THREADS, 0, stream>>>(records, cursor,
                                                             values, px, py, pz, res);

    int nblk3 = (K + 255) / 256;
    unscatter<<<nblk3, 256, 0, stream>>>(inv, res, out, K);
}